// Round 10
// baseline (11342.990 us; speedup 1.0000x reference)
//
#include <hip/hip_runtime.h>
#include <stdint.h>

typedef _Float16 f16x8 __attribute__((ext_vector_type(8)));
typedef _Float16 f16x4 __attribute__((ext_vector_type(4)));
typedef float f32x4 __attribute__((ext_vector_type(4)));

static __device__ __forceinline__ float bf2f(unsigned short u) {
  return __uint_as_float(((unsigned int)u) << 16);
}
static __device__ __forceinline__ unsigned short f2bf(float f) {
  unsigned int u = __float_as_uint(f);
  u = (u + 0x7FFFu + ((u >> 16) & 1u)) >> 16;  // RNE
  return (unsigned short)u;
}
static __device__ __forceinline__ unsigned short f2h(float f) {
  _Float16 h = (_Float16)f;
  return __builtin_bit_cast(unsigned short, h);
}
static __device__ __forceinline__ float h2f(unsigned short b) {
  _Float16 h = __builtin_bit_cast(_Float16, b);
  return (float)h;
}
static __device__ __forceinline__ float sigm(float x) { return 1.0f / (1.0f + __expf(-x)); }
static __device__ __forceinline__ float tanh_fast(float x) {
  float ax = fabsf(x);
  float e = __expf(-2.0f * ax);
  float r = (1.0f - e) / (1.0f + e);
  return copysignf(r, x);
}

// ---------------- dtype probe: 1 = bf16 inputs, 0 = f32 inputs ----------------
__global__ void probe_kernel(const unsigned int* __restrict__ raw, unsigned int* __restrict__ dflag) {
  __shared__ int s;
  int tid = threadIdx.x;
  if (tid == 0) s = 0;
  __syncthreads();
  int v = 0;
  for (int k = 0; k < 4; ++k) {
    unsigned int d = raw[2048 + tid * 4 + k];
    unsigned int lo = d & 0xFFFFu, ex = (lo >> 7) & 0xFFu;
    if (lo == 0u || (ex >= 0x40u && ex <= 0x7Cu)) v++;
  }
  atomicAdd(&s, v);
  __syncthreads();
  if (tid == 0) dflag[0] = (s >= 614) ? 1u : 0u;
}

// ---------------- embedding -> f16 act0 [32768][448], pad cols -> 0 ----------
__global__ void embed_kernel(const int* __restrict__ x, const void* __restrict__ emb,
                             unsigned short* __restrict__ act, const unsigned int* __restrict__ dflag) {
  int idx = blockIdx.x * 256 + threadIdx.x;  // 32768 rows * 56 chunks
  int row = idx / 56, c = idx % 56;
  unsigned short* dst = act + (size_t)row * 448 + c * 8;
  union { uint4 v; unsigned short s[8]; } o;
  if (c < 50) {
    int tok = x[row];
    if (dflag[0]) {
      const unsigned short* e = (const unsigned short*)emb + (size_t)tok * 400 + c * 8;
      union { uint4 v; unsigned short s[8]; } r; r.v = *(const uint4*)e;
#pragma unroll
      for (int k = 0; k < 8; ++k) o.s[k] = f2h(bf2f(r.s[k]));
    } else {
      const float* e = (const float*)emb + (size_t)tok * 400 + c * 8;
      float4 r0 = *(const float4*)e, r1 = *(const float4*)(e + 4);
      const float* p0 = (const float*)&r0; const float* p1 = (const float*)&r1;
#pragma unroll
      for (int k = 0; k < 4; ++k) { o.s[k] = f2h(p0[k]); o.s[4 + k] = f2h(p1[k]); }
    }
  } else {
    o.v.x = o.v.y = o.v.z = o.v.w = 0u;
  }
  *(uint4*)dst = o.v;
}

// ------------- weights/bias -> GROUP-MAJOR padded f16 layouts -----------------
// Row j = G*64 + q*16 + u  <->  unit i = G*16+u, gate q (i,f,g,o).
__global__ void prep_kernel(const void* __restrict__ wih, const void* __restrict__ whh,
                            const void* __restrict__ bih, const void* __restrict__ bhh,
                            unsigned short* __restrict__ WihG, unsigned short* __restrict__ WhhG,
                            float* __restrict__ biasG, int H, int HPo, int din, int dpIn,
                            const unsigned int* __restrict__ dflag) {
  int nb = 4 * HPo, bid = blockIdx.x, tid = threadIdx.x;
  bool isf32 = (dflag[0] == 0u);
  if (bid < 2 * nb) {
    bool ih = bid < nb;
    int j = ih ? bid : bid - nb;
    int i = (j >> 6) * 16 + (j & 15), q = (j >> 4) & 3;
    int cdst = ih ? dpIn : HPo, csrc = ih ? din : H;
    unsigned short* dst = (ih ? WihG : WhhG) + (size_t)j * cdst;
    bool valid = i < H;
    const void* w = ih ? wih : whh;
    for (int m = tid; m < cdst; m += 256) {
      unsigned short v = 0;
      if (valid && m < csrc) {
        if (isf32) v = f2h(((const float*)w)[(size_t)(q * H + i) * csrc + m]);
        else       v = f2h(bf2f(((const unsigned short*)w)[(size_t)(q * H + i) * csrc + m]));
      }
      dst[m] = v;
    }
  } else {
    for (int m = tid; m < nb; m += 256) {
      int i = (m >> 6) * 16 + (m & 15), q = (m >> 4) & 3;
      float v = 0.0f;
      if (i < H) {
        if (isf32) v = ((const float*)bih)[q * H + i] + ((const float*)bhh)[q * H + i];
        else       v = bf2f(((const unsigned short*)bih)[q * H + i]) + bf2f(((const unsigned short*)bhh)[q * H + i]);
      }
      biasG[m] = v;
    }
  }
}

// ---------------- final unpad: act3 f16 [.][448] -> d_out (bf16 or f32) -------
__global__ void unpad_kernel(const unsigned short* __restrict__ act, void* __restrict__ out,
                             const unsigned int* __restrict__ dflag) {
  int idx = blockIdx.x * 256 + threadIdx.x;  // 32768 * 50
  int row = idx / 50, c = idx % 50;
  const unsigned short* src = act + (size_t)row * 448 + c * 8;
  union { uint4 v; unsigned short s[8]; } u; u.v = *(const uint4*)src;
  if (dflag[0]) {
    union { uint4 v; unsigned short s[8]; } o;
#pragma unroll
    for (int k = 0; k < 8; ++k) o.s[k] = f2bf(h2f(u.s[k]));
    *(uint4*)((unsigned short*)out + (size_t)row * 400 + c * 8) = o.v;
  } else {
    float4 o0, o1;
    float* p0 = (float*)&o0; float* p1 = (float*)&o1;
#pragma unroll
    for (int k = 0; k < 4; ++k) { p0[k] = h2f(u.s[k]); p1[k] = h2f(u.s[4 + k]); }
    float* dst = (float*)out + (size_t)row * 400 + c * 8;
    *(float4*)dst = o0; *(float4*)(dst + 4) = o1;
  }
}

// ------------- chunked GEMM: gx = act_chunk @ WihG^T, cell-layout f16 ---------
// gx[((size_t)G*chrows + m)*64 + u*4 + q], G=n>>6, q=(n>>4)&3, u=n&15.
__global__ __launch_bounds__(256, 1) void gemm_xw_kernel(
    const unsigned short* __restrict__ A, const unsigned short* __restrict__ B,
    unsigned short* __restrict__ gx, int K, int chrows) {
  __shared__ unsigned short Asm[128 * 32], Bsm[128 * 32];  // 8KB each, XOR-swizzled
  const int tid = threadIdx.x, lane = tid & 63, wv = tid >> 6;
  const int bm0 = blockIdx.x * 128, bn0 = blockIdx.y * 128;
  f32x4 acc[2][8] = {};
  const int nkt = K >> 5;
  for (int kt = 0; kt < nkt; ++kt) {
    __syncthreads();
#pragma unroll
    for (int j = 0; j < 2; ++j) {
      int idx = tid * 2 + j, r = idx >> 2, c4 = idx & 3;
      uint4 va = *(const uint4*)(A + (size_t)(bm0 + r) * K + kt * 32 + c4 * 8);
      uint4 vb = *(const uint4*)(B + (size_t)(bn0 + r) * K + kt * 32 + c4 * 8);
      int off = (r * 64 + c4 * 16) ^ ((r & 7) << 4);
      *(uint4*)((char*)Asm + off) = va;
      *(uint4*)((char*)Bsm + off) = vb;
    }
    __syncthreads();
    f16x8 af[2], bf[8];
#pragma unroll
    for (int rt = 0; rt < 2; ++rt) {
      int arow = wv * 32 + rt * 16 + (lane & 15);
      int off = (arow * 64 + ((lane >> 4) << 4)) ^ ((arow & 7) << 4);
      af[rt] = *(const f16x8*)((char*)Asm + off);
    }
#pragma unroll
    for (int ct = 0; ct < 8; ++ct) {
      int brow = ct * 16 + (lane & 15);
      int off = (brow * 64 + ((lane >> 4) << 4)) ^ ((brow & 7) << 4);
      bf[ct] = *(const f16x8*)((char*)Bsm + off);
    }
#pragma unroll
    for (int rt = 0; rt < 2; ++rt)
#pragma unroll
      for (int ct = 0; ct < 8; ++ct)
        acc[rt][ct] = __builtin_amdgcn_mfma_f32_16x16x32_f16(af[rt], bf[ct], acc[rt][ct], 0, 0, 0);
  }
#pragma unroll
  for (int ct = 0; ct < 8; ++ct) {
    int n = bn0 + ct * 16 + (lane & 15);
    int G = n >> 6, c = n & 63;
    int cellcol = (c & 15) * 4 + (c >> 4);
#pragma unroll
    for (int rt = 0; rt < 2; ++rt) {
#pragma unroll
      for (int reg = 0; reg < 4; ++reg) {
        int m = bm0 + wv * 32 + rt * 16 + ((lane >> 4) << 2) + reg;
        gx[((size_t)G * chrows + m) * 64 + cellcol] = f2h(acc[rt][ct][reg]);
      }
    }
  }
}

// ---------------- recurrent phase: dual-quarter interleaved -------------------
// Block bid: G = bid>>1 (16-unit group), pr = bid&1 -> quarters qa=2pr, qb=2pr+1
// (16 batch rows each; row quarters are independent recurrences).
// 8 waves split k unevenly: kq<NA -> KTa tiles, else KTb tiles (zero h dup).
// Per iteration: [pollA | gx loads | h_A burst+MFMA | pollB | h_B burst (flies
// under reduceA) | reduceA+publishA+bumpA | MFMA B | reduceB+publishB+bumpB].
// A's flag propagation hides under B's phase and vice versa.
template <int KT>
static __device__ __forceinline__ void loadh(f16x8* hv, const unsigned short* hp) {
#pragma unroll
  for (int kt = 0; kt < KT; ++kt) hv[kt] = *(const f16x8*)(hp + kt * 32);
}
template <int KT, int KTM>
static __device__ __forceinline__ void loadw(f16x8 wreg[4][KTM], const unsigned short* wp, int HP) {
#pragma unroll
  for (int cf = 0; cf < 4; ++cf)
#pragma unroll
    for (int kt = 0; kt < KT; ++kt)
      wreg[cf][kt] = *(const f16x8*)(wp + (size_t)cf * 16 * HP + kt * 32);
}
template <int KT, int KTM>
static __device__ __forceinline__ void mmaq(const f16x8* hv, const f16x8 wreg[4][KTM], f32x4 acc[4]) {
#pragma unroll
  for (int kt = 0; kt < KT; ++kt)
#pragma unroll
    for (int cf = 0; cf < 4; ++cf)
      acc[cf] = __builtin_amdgcn_mfma_f32_16x16x32_f16(hv[kt], wreg[cf][kt], acc[cf], 0, 0, 0);
}

template <int HP, int NA, int KTa, int KTb, int NCNT>
static __device__ __forceinline__ void rec_body(
    const unsigned short* __restrict__ gxAll, unsigned short* __restrict__ actOut,
    const unsigned short* __restrict__ WhhG, const float* __restrict__ biasG,
    unsigned int* __restrict__ cnt, float* __restrict__ cstate,
    int t0, int TS, int chrows, int bid) {
  constexpr int NGRP = HP / 16;
  constexpr unsigned PERQ = (unsigned)(NGRP / NCNT);
  constexpr int KTM = (KTa > KTb) ? KTa : KTb;
  constexpr int GSTR = 72;  // read-2-way, write-4-way banks
  extern __shared__ char smem[];
  float* Gp = (float*)smem;  // [128][GSTR] f32 = 36,864 B
  const int tid = threadIdx.x, lane = tid & 63, wv = tid >> 6;
  const int lrow = lane & 15, kc8 = (lane >> 4) << 3;
  const int G = bid >> 1, pr = bid & 1;
  const int qa = pr * 2, qb = pr * 2 + 1;
  const int kq = wv;
  const int k0 = (kq < NA) ? kq * KTa * 32 : NA * KTa * 32 + (kq - NA) * KTb * 32;
  const bool red = tid < 256;
  const int urow = (tid >> 4) & 15, ui = tid & 15;
  unsigned int* cntA = cnt + qa * 256;
  unsigned int* cntB = cnt + qb * 256;

  f16x8 wreg[4][KTM];
  {
    const unsigned short* wp = WhhG + ((size_t)(G * 64 + lrow)) * HP + k0 + kc8;
    if (kq < NA) loadw<KTa, KTM>(wreg, wp, HP);
    else         loadw<KTb, KTM>(wreg, wp, HP);
  }
  float bs[4] = {0.f, 0.f, 0.f, 0.f};
  float cA = 0.f, cB = 0.f;
  if (red) {
#pragma unroll
    for (int q = 0; q < 4; ++q) bs[q] = biasG[G * 64 + q * 16 + ui];
    if (t0 > 0) {
      cA = cstate[(qa * 16 + urow) * HP + G * 16 + ui];
      cB = cstate[(qb * 16 + urow) * HP + G * 16 + ui];
    }
  }
  __syncthreads();

  auto pollq = [&](unsigned int* cq, unsigned need) {
    while (true) {
      int ok = 1;
      if (tid < NCNT)
        ok = (__hip_atomic_load(cq + tid * 32, __ATOMIC_RELAXED, __HIP_MEMORY_SCOPE_AGENT) >= need);
      if (__syncthreads_and(ok)) break;
      __builtin_amdgcn_s_sleep(1);
    }
    asm volatile("" ::: "memory");
  };
  auto stGp = [&](f32x4 acc[4]) {
    const int br = kq * 16 + (lane >> 4) * 4;
#pragma unroll
    for (int cf = 0; cf < 4; ++cf)
#pragma unroll
      for (int r = 0; r < 4; ++r)
        Gp[(br + r) * GSTR + cf * 16 + lrow] = acc[cf][r];
  };
  auto reduceq = [&](int q, int t, float& cc, f16x4 gxv, bool useGp) {
    float gi = (float)gxv[0] + bs[0], gf = (float)gxv[1] + bs[1];
    float gg = (float)gxv[2] + bs[2], go = (float)gxv[3] + bs[3];
    if (useGp) {
#pragma unroll
      for (int k = 0; k < 8; ++k) {
        const int base = (k * 16 + urow) * GSTR + ui;
        gi += Gp[base];
        gf += Gp[base + 16];
        gg += Gp[base + 32];
        go += Gp[base + 48];
      }
    }
    float ig = sigm(gi), fg = sigm(gf), gt = tanh_fast(gg), og = sigm(go);
    cc = fg * cc + ig * gt;
    unsigned short hb = f2h(og * tanh_fast(cc));
    int other = __shfl_xor((int)hb, 1);
    if ((ui & 1) == 0) {
      unsigned int pk = ((unsigned)hb & 0xFFFFu) | ((unsigned)other << 16);
      __hip_atomic_store((unsigned int*)(actOut + ((size_t)t * 64 + q * 16 + urow) * HP + G * 16 + ui),
                         pk, __ATOMIC_RELAXED, __HIP_MEMORY_SCOPE_AGENT);
    }
  };

  const int tend = t0 + TS;
  for (int t = t0; t < tend; ++t) {
    const int tr = t - t0;
    // ================= quarter A =================
    if (t > 0) pollq(cntA, PERQ * (unsigned)t);
    f16x4 gxa = {}, gxb = {};
    if (red) {
      gxa = *(const f16x4*)(gxAll + ((size_t)G * chrows + tr * 64 + qa * 16 + urow) * 64 + ui * 4);
      gxb = *(const f16x4*)(gxAll + ((size_t)G * chrows + tr * 64 + qb * 16 + urow) * 64 + ui * 4);
    }
    if (t > 0) {
      f16x8 hv[KTM];
      const unsigned short* hpA = actOut + ((size_t)(t - 1) * 64 + qa * 16 + lrow) * HP + k0 + kc8;
      f32x4 acc[4] = {};
      if (kq < NA) { loadh<KTa>(hv, hpA); mmaq<KTa, KTM>(hv, wreg, acc); }
      else         { loadh<KTb>(hv, hpA); mmaq<KTb, KTM>(hv, wreg, acc); }
      stGp(acc);
    }
    // poll B early; its barrier also orders A's Gp writes for the reduce
    if (t > 0) pollq(cntB, PERQ * (unsigned)t);
    else __syncthreads();
    // issue B's h burst now -> flies under reduce A
    f16x8 hvB[KTM];
    if (t > 0) {
      const unsigned short* hpB = actOut + ((size_t)(t - 1) * 64 + qb * 16 + lrow) * HP + k0 + kc8;
      if (kq < NA) loadh<KTa>(hvB, hpB);
      else         loadh<KTb>(hvB, hpB);
    }
    if (red) reduceq(qa, t, cA, gxa, t > 0);
    asm volatile("s_waitcnt vmcnt(0)" ::: "memory");
    __syncthreads();
    if (tid == 0)
      __hip_atomic_fetch_add(cntA + (G & (NCNT - 1)) * 32, 1u, __ATOMIC_RELEASE, __HIP_MEMORY_SCOPE_AGENT);
    // ================= quarter B =================
    if (t > 0) {
      f32x4 acc[4] = {};
      if (kq < NA) mmaq<KTa, KTM>(hvB, wreg, acc);
      else         mmaq<KTb, KTM>(hvB, wreg, acc);
      stGp(acc);
    }
    asm volatile("s_waitcnt lgkmcnt(0)" ::: "memory");
    __builtin_amdgcn_s_barrier();
    __builtin_amdgcn_sched_barrier(0);
    if (red) reduceq(qb, t, cB, gxb, t > 0);
    asm volatile("s_waitcnt vmcnt(0)" ::: "memory");
    __syncthreads();
    if (tid == 0)
      __hip_atomic_fetch_add(cntB + (G & (NCNT - 1)) * 32, 1u, __ATOMIC_RELEASE, __HIP_MEMORY_SCOPE_AGENT);
  }
  if (red) {
    cstate[(qa * 16 + urow) * HP + G * 16 + ui] = cA;
    cstate[(qb * 16 + urow) * HP + G * 16 + ui] = cB;
  }
}

__global__ __launch_bounds__(512, 1) void lstm_rec1152(
    const unsigned short* __restrict__ gxAll, unsigned short* __restrict__ actOut,
    const unsigned short* __restrict__ WhhG, const float* __restrict__ biasG,
    unsigned int* __restrict__ cnt, float* __restrict__ cstate, int t0, int TS, int chrows) {
  rec_body<1152, 4, 4, 5, 8>(gxAll, actOut, WhhG, biasG, cnt, cstate, t0, TS, chrows, blockIdx.x);
}
__global__ __launch_bounds__(512, 1) void lstm_rec448(
    const unsigned short* __restrict__ gxAll, unsigned short* __restrict__ actOut,
    const unsigned short* __restrict__ WhhG, const float* __restrict__ biasG,
    unsigned int* __restrict__ cnt, float* __restrict__ cstate, int t0, int TS, int chrows) {
  rec_body<448, 6, 2, 1, 4>(gxAll, actOut, WhhG, biasG, cnt, cstate, t0, TS, chrows, blockIdx.x);
}

// ------------------------------- host ----------------------------------------
extern "C" void kernel_launch(void* const* d_in, const int* in_sizes, int n_in,
                              void* d_out, int out_size, void* d_ws, size_t ws_size,
                              hipStream_t stream) {
  (void)in_sizes; (void)n_in; (void)out_size;
  const int* x = (const int*)d_in[0];
  const void* emb = d_in[1];
  const void* wih[3] = {d_in[2], d_in[6], d_in[10]};
  const void* whh[3] = {d_in[3], d_in[7], d_in[11]};
  const void* bih[3] = {d_in[4], d_in[8], d_in[12]};
  const void* bhh[3] = {d_in[5], d_in[9], d_in[13]};

  char* ws = (char*)d_ws;
  size_t off = 0;
  unsigned short* act0 = (unsigned short*)(ws + off); off += (size_t)32768 * 448 * 2;
  unsigned short* act1 = (unsigned short*)(ws + off); off += (size_t)32768 * 1152 * 2;
  unsigned short* act2 = (unsigned short*)(ws + off); off += (size_t)32768 * 1152 * 2;
  unsigned short* act3 = act0;  // alias: act0 dead after L0 GEMM chunks
  unsigned short* WihG = (unsigned short*)(ws + off); off += (size_t)4608 * 1152 * 2;
  unsigned short* WhhG = (unsigned short*)(ws + off); off += (size_t)4608 * 1152 * 2;
  float* biasG = (float*)(ws + off); off += (size_t)4608 * 4;
  float* cstate = (float*)(ws + off); off += (size_t)64 * 1152 * 4;
  unsigned int* cnt = (unsigned int*)(ws + off); off += 4096;
  unsigned int* dflag = (unsigned int*)(ws + off); off += 256;
  unsigned short* gx = (unsigned short*)(ws + off);

  // gx chunk sizing from remaining workspace (589,824 B per timestep)
  size_t avail = (ws_size > off) ? (ws_size - off) : 0;
  int CH = 512;
  while (CH > 32 && (size_t)CH * 589824 > avail) CH >>= 1;
  const int chrows = CH * 64, nch = 512 / CH;

  const size_t ldsrec = 128 * 72 * 4;  // 36,864 B

  probe_kernel<<<1, 256, 0, stream>>>((const unsigned int*)emb, dflag);
  embed_kernel<<<7168, 256, 0, stream>>>(x, emb, act0, dflag);

  // ---- Layer 0: din 400(->448) -> H 1150(->1152)
  prep_kernel<<<2 * 4608 + 1, 256, 0, stream>>>(wih[0], whh[0], bih[0], bhh[0],
                                                WihG, WhhG, biasG, 1150, 1152, 400, 448, dflag);
  hipMemsetAsync(cnt, 0, 4096, stream);
  for (int c = 0; c < nch; ++c) {
    gemm_xw_kernel<<<dim3(CH / 2, 36), 256, 0, stream>>>(act0 + (size_t)c * chrows * 448, WihG, gx, 448, chrows);
    lstm_rec1152<<<144, 512, ldsrec, stream>>>(gx, act1, WhhG, biasG, cnt, cstate, c * CH, CH, chrows);
  }

  // ---- Layer 1: 1150(->1152) -> 1150(->1152)
  prep_kernel<<<2 * 4608 + 1, 256, 0, stream>>>(wih[1], whh[1], bih[1], bhh[1],
                                                WihG, WhhG, biasG, 1150, 1152, 1150, 1152, dflag);
  hipMemsetAsync(cnt, 0, 4096, stream);
  for (int c = 0; c < nch; ++c) {
    gemm_xw_kernel<<<dim3(CH / 2, 36), 256, 0, stream>>>(act1 + (size_t)c * chrows * 1152, WihG, gx, 1152, chrows);
    lstm_rec1152<<<144, 512, ldsrec, stream>>>(gx, act2, WhhG, biasG, cnt, cstate, c * CH, CH, chrows);
  }

  // ---- Layer 2: 1150(->1152) -> H 400(->448)
  prep_kernel<<<2 * 1792 + 1, 256, 0, stream>>>(wih[2], whh[2], bih[2], bhh[2],
                                                WihG, WhhG, biasG, 400, 448, 1150, 1152, dflag);
  hipMemsetAsync(cnt, 0, 4096, stream);
  for (int c = 0; c < nch; ++c) {
    gemm_xw_kernel<<<dim3(CH / 2, 14), 256, 0, stream>>>(act2 + (size_t)c * chrows * 1152, WihG, gx, 1152, chrows);
    lstm_rec448<<<56, 512, ldsrec, stream>>>(gx, act3, WhhG, biasG, cnt, cstate, c * CH, CH, chrows);
  }

  unpad_kernel<<<6400, 256, 0, stream>>>(act3, d_out, dflag);
}

// Round 11
// 9895.997 us; speedup vs baseline: 1.1462x; 1.1462x over previous
//
#include <hip/hip_runtime.h>
#include <stdint.h>

typedef _Float16 f16x8 __attribute__((ext_vector_type(8)));
typedef _Float16 f16x4 __attribute__((ext_vector_type(4)));
typedef float f32x4 __attribute__((ext_vector_type(4)));

static __device__ __forceinline__ float bf2f(unsigned short u) {
  return __uint_as_float(((unsigned int)u) << 16);
}
static __device__ __forceinline__ unsigned short f2bf(float f) {
  unsigned int u = __float_as_uint(f);
  u = (u + 0x7FFFu + ((u >> 16) & 1u)) >> 16;  // RNE
  return (unsigned short)u;
}
static __device__ __forceinline__ unsigned short f2h(float f) {
  _Float16 h = (_Float16)f;
  return __builtin_bit_cast(unsigned short, h);
}
static __device__ __forceinline__ float h2f(unsigned short b) {
  _Float16 h = __builtin_bit_cast(_Float16, b);
  return (float)h;
}
static __device__ __forceinline__ float sigm(float x) { return 1.0f / (1.0f + __expf(-x)); }
static __device__ __forceinline__ float tanh_fast(float x) {
  float ax = fabsf(x);
  float e = __expf(-2.0f * ax);
  float r = (1.0f - e) / (1.0f + e);
  return copysignf(r, x);
}

// ---------------- dtype probe: 1 = bf16 inputs, 0 = f32 inputs ----------------
__global__ void probe_kernel(const unsigned int* __restrict__ raw, unsigned int* __restrict__ dflag) {
  __shared__ int s;
  int tid = threadIdx.x;
  if (tid == 0) s = 0;
  __syncthreads();
  int v = 0;
  for (int k = 0; k < 4; ++k) {
    unsigned int d = raw[2048 + tid * 4 + k];
    unsigned int lo = d & 0xFFFFu, ex = (lo >> 7) & 0xFFu;
    if (lo == 0u || (ex >= 0x40u && ex <= 0x7Cu)) v++;
  }
  atomicAdd(&s, v);
  __syncthreads();
  if (tid == 0) dflag[0] = (s >= 614) ? 1u : 0u;
}

// ---------------- embedding -> f16 act0 [32768][448], pad cols -> 0 ----------
__global__ void embed_kernel(const int* __restrict__ x, const void* __restrict__ emb,
                             unsigned short* __restrict__ act, const unsigned int* __restrict__ dflag) {
  int idx = blockIdx.x * 256 + threadIdx.x;  // 32768 rows * 56 chunks
  int row = idx / 56, c = idx % 56;
  unsigned short* dst = act + (size_t)row * 448 + c * 8;
  union { uint4 v; unsigned short s[8]; } o;
  if (c < 50) {
    int tok = x[row];
    if (dflag[0]) {
      const unsigned short* e = (const unsigned short*)emb + (size_t)tok * 400 + c * 8;
      union { uint4 v; unsigned short s[8]; } r; r.v = *(const uint4*)e;
#pragma unroll
      for (int k = 0; k < 8; ++k) o.s[k] = f2h(bf2f(r.s[k]));
    } else {
      const float* e = (const float*)emb + (size_t)tok * 400 + c * 8;
      float4 r0 = *(const float4*)e, r1 = *(const float4*)(e + 4);
      const float* p0 = (const float*)&r0; const float* p1 = (const float*)&r1;
#pragma unroll
      for (int k = 0; k < 4; ++k) { o.s[k] = f2h(p0[k]); o.s[4 + k] = f2h(p1[k]); }
    }
  } else {
    o.v.x = o.v.y = o.v.z = o.v.w = 0u;
  }
  *(uint4*)dst = o.v;
}

// ------------- weights/bias -> GROUP-MAJOR padded f16 layouts -----------------
// Group width GW (96 or 64): row j = G*GW + q*(GW/4) + u <-> unit i = G*(GW/4)+u.
__global__ void prep_kernel(const void* __restrict__ wih, const void* __restrict__ whh,
                            const void* __restrict__ bih, const void* __restrict__ bhh,
                            unsigned short* __restrict__ WihG, unsigned short* __restrict__ WhhG,
                            float* __restrict__ biasG, int H, int HPo, int din, int dpIn, int GW,
                            const unsigned int* __restrict__ dflag) {
  int nb = 4 * HPo, bid = blockIdx.x, tid = threadIdx.x;
  int upg = GW >> 2;
  bool isf32 = (dflag[0] == 0u);
  if (bid < 2 * nb) {
    bool ih = bid < nb;
    int j = ih ? bid : bid - nb;
    int rj = j % GW;
    int i = (j / GW) * upg + rj % upg, q = rj / upg;
    int cdst = ih ? dpIn : HPo, csrc = ih ? din : H;
    unsigned short* dst = (ih ? WihG : WhhG) + (size_t)j * cdst;
    bool valid = i < H;
    const void* w = ih ? wih : whh;
    for (int m = tid; m < cdst; m += 256) {
      unsigned short v = 0;
      if (valid && m < csrc) {
        if (isf32) v = f2h(((const float*)w)[(size_t)(q * H + i) * csrc + m]);
        else       v = f2h(bf2f(((const unsigned short*)w)[(size_t)(q * H + i) * csrc + m]));
      }
      dst[m] = v;
    }
  } else {
    for (int m = tid; m < nb; m += 256) {
      int rj = m % GW;
      int i = (m / GW) * upg + rj % upg, q = rj / upg;
      float v = 0.0f;
      if (i < H) {
        if (isf32) v = ((const float*)bih)[q * H + i] + ((const float*)bhh)[q * H + i];
        else       v = bf2f(((const unsigned short*)bih)[q * H + i]) + bf2f(((const unsigned short*)bhh)[q * H + i]);
      }
      biasG[m] = v;
    }
  }
}

// ---------------- final unpad: act3 f16 [.][448] -> d_out (bf16 or f32) -------
__global__ void unpad_kernel(const unsigned short* __restrict__ act, void* __restrict__ out,
                             const unsigned int* __restrict__ dflag) {
  int idx = blockIdx.x * 256 + threadIdx.x;  // 32768 * 50
  int row = idx / 50, c = idx % 50;
  const unsigned short* src = act + (size_t)row * 448 + c * 8;
  union { uint4 v; unsigned short s[8]; } u; u.v = *(const uint4*)src;
  if (dflag[0]) {
    union { uint4 v; unsigned short s[8]; } o;
#pragma unroll
    for (int k = 0; k < 8; ++k) o.s[k] = f2bf(h2f(u.s[k]));
    *(uint4*)((unsigned short*)out + (size_t)row * 400 + c * 8) = o.v;
  } else {
    float4 o0, o1;
    float* p0 = (float*)&o0; float* p1 = (float*)&o1;
#pragma unroll
    for (int k = 0; k < 4; ++k) { p0[k] = h2f(u.s[k]); p1[k] = h2f(u.s[4 + k]); }
    float* dst = (float*)out + (size_t)row * 400 + c * 8;
    *(float4*)dst = o0; *(float4*)(dst + 4) = o1;
  }
}

// ------------- chunked GEMM: gx = act_chunk @ WihG^T, cell-layout f16 ---------
// Output cell: gx[((size_t)G*chrows + m)*GW + u*4 + q], G=n/GW, u=(n%GW)%(GW/4),
// q=(n%GW)/(GW/4).
__global__ __launch_bounds__(256, 1) void gemm_xw_kernel(
    const unsigned short* __restrict__ A, const unsigned short* __restrict__ B,
    unsigned short* __restrict__ gx, int K, int chrows, int GW) {
  __shared__ unsigned short Asm[128 * 32], Bsm[128 * 32];  // 8KB each, XOR-swizzled
  const int tid = threadIdx.x, lane = tid & 63, wv = tid >> 6;
  const int bm0 = blockIdx.x * 128, bn0 = blockIdx.y * 128;
  const int upg = GW >> 2;
  f32x4 acc[2][8] = {};
  const int nkt = K >> 5;
  for (int kt = 0; kt < nkt; ++kt) {
    __syncthreads();
#pragma unroll
    for (int j = 0; j < 2; ++j) {
      int idx = tid * 2 + j, r = idx >> 2, c4 = idx & 3;
      uint4 va = *(const uint4*)(A + (size_t)(bm0 + r) * K + kt * 32 + c4 * 8);
      uint4 vb = *(const uint4*)(B + (size_t)(bn0 + r) * K + kt * 32 + c4 * 8);
      int off = (r * 64 + c4 * 16) ^ ((r & 7) << 4);
      *(uint4*)((char*)Asm + off) = va;
      *(uint4*)((char*)Bsm + off) = vb;
    }
    __syncthreads();
    f16x8 af[2], bf[8];
#pragma unroll
    for (int rt = 0; rt < 2; ++rt) {
      int arow = wv * 32 + rt * 16 + (lane & 15);
      int off = (arow * 64 + ((lane >> 4) << 4)) ^ ((arow & 7) << 4);
      af[rt] = *(const f16x8*)((char*)Asm + off);
    }
#pragma unroll
    for (int ct = 0; ct < 8; ++ct) {
      int brow = ct * 16 + (lane & 15);
      int off = (brow * 64 + ((lane >> 4) << 4)) ^ ((brow & 7) << 4);
      bf[ct] = *(const f16x8*)((char*)Bsm + off);
    }
#pragma unroll
    for (int rt = 0; rt < 2; ++rt)
#pragma unroll
      for (int ct = 0; ct < 8; ++ct)
        acc[rt][ct] = __builtin_amdgcn_mfma_f32_16x16x32_f16(af[rt], bf[ct], acc[rt][ct], 0, 0, 0);
  }
#pragma unroll
  for (int ct = 0; ct < 8; ++ct) {
    int n = bn0 + ct * 16 + (lane & 15);
    int G = n / GW, c = n % GW;
    int cellcol = (c % upg) * 4 + (c / upg);
#pragma unroll
    for (int rt = 0; rt < 2; ++rt) {
#pragma unroll
      for (int reg = 0; reg < 4; ++reg) {
        int m = bm0 + wv * 32 + rt * 16 + ((lane >> 4) << 2) + reg;
        gx[((size_t)G * chrows + m) * GW + cellcol] = f2h(acc[rt][ct][reg]);
      }
    }
  }
}

// ---------------- rec1152: 24 units x 16 rows per block, 192 blocks ------------
// bid: G = bid>>2 (24-unit group, 0..47), rq = bid&3 (16-row quarter).
// Row quarters are independent -> 4 counter groups (8 sub-counters, PERQ=6).
// 8 waves = 8 uneven k-slices (4x160 KT=5, 4x128 KT=4). Per-CU h fill:
// 16 rows x 1152 x 2B = 36.9 KB/step. Per-step skeleton identical to R9:
// poll -> gx -> burst h + MFMA -> LDS-only barrier -> reduce -> publish ->
// vmcnt drain + sync -> release.
__global__ __launch_bounds__(512, 1) void lstm_rec1152(
    const unsigned short* __restrict__ gxAll, unsigned short* __restrict__ actOut,
    const unsigned short* __restrict__ WhhG, const float* __restrict__ biasG,
    unsigned int* __restrict__ cnt, float* __restrict__ cstate,
    int t0, int TS, int chrows) {
  constexpr int HP = 1152, GSTR = 100;
  __shared__ float Gp[128 * GSTR];  // 51,200 B
  const int tid = threadIdx.x, lane = tid & 63, wv = tid >> 6;
  const int lrow = lane & 15, kc8 = (lane >> 4) << 3;
  const int G = blockIdx.x >> 2, rq = blockIdx.x & 3;
  const int k0 = (wv < 4) ? wv * 160 : 640 + (wv - 4) * 128;
  const int urow = tid >> 5, ui = tid & 31;
  const bool red = ui < 24;
  unsigned int* mycnt = cnt + rq * 256;

  f16x8 wreg[6][5];
  {
    const unsigned short* wp = WhhG + ((size_t)(G * 96 + lrow)) * HP + k0 + kc8;
    if (wv < 4) {
#pragma unroll
      for (int cf = 0; cf < 6; ++cf)
#pragma unroll
        for (int kt = 0; kt < 5; ++kt)
          wreg[cf][kt] = *(const f16x8*)(wp + (size_t)cf * 16 * HP + kt * 32);
    } else {
#pragma unroll
      for (int cf = 0; cf < 6; ++cf)
#pragma unroll
        for (int kt = 0; kt < 4; ++kt)
          wreg[cf][kt] = *(const f16x8*)(wp + (size_t)cf * 16 * HP + kt * 32);
    }
  }
  float bs[4] = {0.f, 0.f, 0.f, 0.f};
  float creg = 0.0f;
  if (red) {
#pragma unroll
    for (int q = 0; q < 4; ++q) bs[q] = biasG[G * 96 + q * 24 + ui];
    if (t0 > 0) creg = cstate[(rq * 16 + urow) * HP + G * 24 + ui];
  }
  __syncthreads();

  const int tend = t0 + TS;
  for (int t = t0; t < tend; ++t) {
    // ---- wait for this row-quarter's 48 blocks to publish h(t-1)
    if (t > 0) {
      while (true) {
        int ok = 1;
        if (tid < 8)
          ok = (__hip_atomic_load(mycnt + tid * 32, __ATOMIC_RELAXED, __HIP_MEMORY_SCOPE_AGENT) >= 6u * (unsigned)t);
        if (__syncthreads_and(ok)) break;
        __builtin_amdgcn_s_sleep(1);
      }
      asm volatile("" ::: "memory");
    }
    // ---- gx(t) issued now; consumed in reduce (hides under MFMA phase)
    f16x4 gxv = {};
    if (red)
      gxv = *(const f16x4*)(gxAll + ((size_t)G * chrows + (t - t0) * 64 + rq * 16 + urow) * 96 + ui * 4);
    // ---- h-part: burst-load this wave's 16 rows x k-slice, then MFMA
    if (t > 0) {
      f16x8 hv[5];
      const unsigned short* hp = actOut + ((size_t)(t - 1) * 64 + rq * 16 + lrow) * HP + k0 + kc8;
      f32x4 acc[6] = {};
      if (wv < 4) {
#pragma unroll
        for (int kt = 0; kt < 5; ++kt) hv[kt] = *(const f16x8*)(hp + kt * 32);
#pragma unroll
        for (int kt = 0; kt < 5; ++kt)
#pragma unroll
          for (int cf = 0; cf < 6; ++cf)
            acc[cf] = __builtin_amdgcn_mfma_f32_16x16x32_f16(hv[kt], wreg[cf][kt], acc[cf], 0, 0, 0);
      } else {
#pragma unroll
        for (int kt = 0; kt < 4; ++kt) hv[kt] = *(const f16x8*)(hp + kt * 32);
#pragma unroll
        for (int kt = 0; kt < 4; ++kt)
#pragma unroll
          for (int cf = 0; cf < 6; ++cf)
            acc[cf] = __builtin_amdgcn_mfma_f32_16x16x32_f16(hv[kt], wreg[cf][kt], acc[cf], 0, 0, 0);
      }
      const int br = (lane >> 4) * 4;
#pragma unroll
      for (int cf = 0; cf < 6; ++cf)
#pragma unroll
        for (int r = 0; r < 4; ++r)
          Gp[(wv * 16 + br + r) * GSTR + cf * 16 + lrow] = acc[cf][r];
    }
    // ---- LDS-only barrier: gx load stays in flight (no vmcnt drain)
    asm volatile("s_waitcnt lgkmcnt(0)" ::: "memory");
    __builtin_amdgcn_s_barrier();
    __builtin_amdgcn_sched_barrier(0);
    // ---- reduce + gate update (cell = row urow, unit ui; 384 active threads)
    if (red) {
      float gi = (float)gxv[0] + bs[0], gf = (float)gxv[1] + bs[1];
      float gg = (float)gxv[2] + bs[2], go = (float)gxv[3] + bs[3];
      if (t > 0) {
#pragma unroll
        for (int k = 0; k < 8; ++k) {
          const int base = (k * 16 + urow) * GSTR + ui;
          gi += Gp[base];
          gf += Gp[base + 24];
          gg += Gp[base + 48];
          go += Gp[base + 72];
        }
      }
      float ig = sigm(gi), fg = sigm(gf), gt = tanh_fast(gg), og = sigm(go);
      creg = fg * creg + ig * gt;
      unsigned short hb = f2h(og * tanh_fast(creg));
      int other = __shfl_xor((int)hb, 1);
      if ((ui & 1) == 0) {
        unsigned int pk = ((unsigned)hb & 0xFFFFu) | ((unsigned)other << 16);
        __hip_atomic_store((unsigned int*)(actOut + ((size_t)t * 64 + rq * 16 + urow) * HP + G * 24 + ui),
                           pk, __ATOMIC_RELAXED, __HIP_MEMORY_SCOPE_AGENT);
      }
    }
    // ---- drain h stores, sync, release arrival
    asm volatile("s_waitcnt vmcnt(0)" ::: "memory");
    __syncthreads();
    if (tid == 0)
      __hip_atomic_fetch_add(mycnt + (G & 7) * 32, 1u, __ATOMIC_RELEASE, __HIP_MEMORY_SCOPE_AGENT);
  }
  if (red) cstate[(rq * 16 + urow) * HP + G * 24 + ui] = creg;
}

// ---------------- rec448: R9-proven 16 units x 32 rows, 56 blocks --------------
__global__ __launch_bounds__(512, 1) void lstm_rec448(
    const unsigned short* __restrict__ gxAll, unsigned short* __restrict__ actOut,
    const unsigned short* __restrict__ WhhG, const float* __restrict__ biasG,
    unsigned int* __restrict__ cnt, float* __restrict__ cstate,
    int t0, int TS, int chrows) {
  constexpr int HP = 448, GSTR = 68, KT = 7;
  __shared__ float Gp[64 * GSTR];  // 17,408 B
  const int tid = threadIdx.x, lane = tid & 63, wv = tid >> 6;
  const int kq = wv & 1, t2 = wv >> 1;
  const int nq = t2 & 1, mh = t2 >> 1;
  const int lrow = lane & 15, kc8 = (lane >> 4) << 3;
  const int G = blockIdx.x >> 1, bh = blockIdx.x & 1;
  const int urow = tid >> 4, ui = tid & 15;
  unsigned int* mycnt = cnt + (size_t)bh * 256;

  float bs[4];
  float creg = 0.0f;
  f16x8 wreg[2][KT];
  {
    const unsigned short* wbase = WhhG + (size_t)G * 64 * HP + kq * 224 + kc8;
#pragma unroll
    for (int cf = 0; cf < 2; ++cf) {
      const unsigned short* wp = wbase + (size_t)((nq * 2 + cf) * 16 + lrow) * HP;
#pragma unroll
      for (int kt = 0; kt < KT; ++kt) wreg[cf][kt] = *(const f16x8*)(wp + kt * 32);
    }
#pragma unroll
    for (int q = 0; q < 4; ++q) bs[q] = biasG[G * 64 + q * 16 + ui];
    if (t0 > 0) creg = cstate[(bh * 32 + urow) * HP + G * 16 + ui];
  }
  __syncthreads();

  const int tend = t0 + TS;
  for (int t = t0; t < tend; ++t) {
    if (t > 0) {
      while (true) {
        int ok = 1;
        if (tid < 4)
          ok = (__hip_atomic_load(mycnt + tid * 32, __ATOMIC_RELAXED, __HIP_MEMORY_SCOPE_AGENT) >= 7u * (unsigned)t);
        if (__syncthreads_and(ok)) break;
        __builtin_amdgcn_s_sleep(1);
      }
      asm volatile("" ::: "memory");
    }
    f16x4 gxv = *(const f16x4*)(gxAll + ((size_t)G * chrows + (t - t0) * 64 + bh * 32 + urow) * 64 + ui * 4);
    if (t > 0) {
      f16x8 hv[KT];
      const unsigned short* hp =
          actOut + ((size_t)(t - 1) * 64 + bh * 32 + mh * 16 + lrow) * HP + kq * 224 + kc8;
#pragma unroll
      for (int kt = 0; kt < KT; ++kt) hv[kt] = *(const f16x8*)(hp + kt * 32);
      f32x4 a[2] = {};
#pragma unroll
      for (int kt = 0; kt < KT; ++kt)
#pragma unroll
        for (int cf = 0; cf < 2; ++cf)
          a[cf] = __builtin_amdgcn_mfma_f32_16x16x32_f16(hv[kt], wreg[cf][kt], a[cf], 0, 0, 0);
      const int br = kq * 32 + mh * 16 + (lane >> 4) * 4;
#pragma unroll
      for (int cf = 0; cf < 2; ++cf)
#pragma unroll
        for (int r = 0; r < 4; ++r)
          Gp[(br + r) * GSTR + (nq * 2 + cf) * 16 + lrow] = a[cf][r];
    }
    asm volatile("s_waitcnt lgkmcnt(0)" ::: "memory");
    __builtin_amdgcn_s_barrier();
    __builtin_amdgcn_sched_barrier(0);
    float gi = (float)gxv[0] + bs[0], gf = (float)gxv[1] + bs[1];
    float gg = (float)gxv[2] + bs[2], go = (float)gxv[3] + bs[3];
    if (t > 0) {
#pragma unroll
      for (int k = 0; k < 2; ++k) {
        const int base = (k * 32 + urow) * GSTR + ui;
        gi += Gp[base];
        gf += Gp[base + 16];
        gg += Gp[base + 32];
        go += Gp[base + 48];
      }
    }
    float ig = sigm(gi), fg = sigm(gf), gt = tanh_fast(gg), og = sigm(go);
    creg = fg * creg + ig * gt;
    unsigned short hb = f2h(og * tanh_fast(creg));
    int other = __shfl_xor((int)hb, 1);
    if ((ui & 1) == 0) {
      unsigned int pk = ((unsigned)hb & 0xFFFFu) | ((unsigned)other << 16);
      __hip_atomic_store((unsigned int*)(actOut + ((size_t)t * 64 + bh * 32 + urow) * HP + G * 16 + ui),
                         pk, __ATOMIC_RELAXED, __HIP_MEMORY_SCOPE_AGENT);
    }
    asm volatile("s_waitcnt vmcnt(0)" ::: "memory");
    __syncthreads();
    if (tid == 0)
      __hip_atomic_fetch_add(mycnt + (G & 3) * 32, 1u, __ATOMIC_RELEASE, __HIP_MEMORY_SCOPE_AGENT);
  }
  cstate[(bh * 32 + urow) * HP + G * 16 + ui] = creg;
}

// ------------------------------- host ----------------------------------------
extern "C" void kernel_launch(void* const* d_in, const int* in_sizes, int n_in,
                              void* d_out, int out_size, void* d_ws, size_t ws_size,
                              hipStream_t stream) {
  (void)in_sizes; (void)n_in; (void)out_size;
  const int* x = (const int*)d_in[0];
  const void* emb = d_in[1];
  const void* wih[3] = {d_in[2], d_in[6], d_in[10]};
  const void* whh[3] = {d_in[3], d_in[7], d_in[11]};
  const void* bih[3] = {d_in[4], d_in[8], d_in[12]};
  const void* bhh[3] = {d_in[5], d_in[9], d_in[13]};

  char* ws = (char*)d_ws;
  size_t off = 0;
  unsigned short* act0 = (unsigned short*)(ws + off); off += (size_t)32768 * 448 * 2;
  unsigned short* act1 = (unsigned short*)(ws + off); off += (size_t)32768 * 1152 * 2;
  unsigned short* act2 = (unsigned short*)(ws + off); off += (size_t)32768 * 1152 * 2;
  unsigned short* act3 = act0;  // alias: act0 dead after L0 GEMM chunks
  unsigned short* WihG = (unsigned short*)(ws + off); off += (size_t)4608 * 1152 * 2;
  unsigned short* WhhG = (unsigned short*)(ws + off); off += (size_t)4608 * 1152 * 2;
  float* biasG = (float*)(ws + off); off += (size_t)4608 * 4;
  float* cstate = (float*)(ws + off); off += (size_t)64 * 1152 * 4;
  unsigned int* cnt = (unsigned int*)(ws + off); off += 4096;
  unsigned int* dflag = (unsigned int*)(ws + off); off += 256;
  unsigned short* gx = (unsigned short*)(ws + off);

  // gx chunk sizing from remaining workspace (589,824 B per timestep)
  size_t avail = (ws_size > off) ? (ws_size - off) : 0;
  int CH = 512;
  while (CH > 32 && (size_t)CH * 589824 > avail) CH >>= 1;
  const int chrows = CH * 64, nch = 512 / CH;

  probe_kernel<<<1, 256, 0, stream>>>((const unsigned int*)emb, dflag);
  embed_kernel<<<7168, 256, 0, stream>>>(x, emb, act0, dflag);

  // ---- Layer 0: din 400(->448) -> H 1150(->1152), GW=96 layouts
  prep_kernel<<<2 * 4608 + 1, 256, 0, stream>>>(wih[0], whh[0], bih[0], bhh[0],
                                                WihG, WhhG, biasG, 1150, 1152, 400, 448, 96, dflag);
  hipMemsetAsync(cnt, 0, 4096, stream);
  for (int c = 0; c < nch; ++c) {
    gemm_xw_kernel<<<dim3(CH / 2, 36), 256, 0, stream>>>(act0 + (size_t)c * chrows * 448, WihG, gx, 448, chrows, 96);
    lstm_rec1152<<<192, 512, 0, stream>>>(gx, act1, WhhG, biasG, cnt, cstate, c * CH, CH, chrows);
  }

  // ---- Layer 1: 1150(->1152) -> 1150(->1152), GW=96 layouts
  prep_kernel<<<2 * 4608 + 1, 256, 0, stream>>>(wih[1], whh[1], bih[1], bhh[1],
                                                WihG, WhhG, biasG, 1150, 1152, 1150, 1152, 96, dflag);
  hipMemsetAsync(cnt, 0, 4096, stream);
  for (int c = 0; c < nch; ++c) {
    gemm_xw_kernel<<<dim3(CH / 2, 36), 256, 0, stream>>>(act1 + (size_t)c * chrows * 1152, WihG, gx, 1152, chrows, 96);
    lstm_rec1152<<<192, 512, 0, stream>>>(gx, act2, WhhG, biasG, cnt, cstate, c * CH, CH, chrows);
  }

  // ---- Layer 2: 1150(->1152) -> H 400(->448), GW=64 layouts (R9 path)
  prep_kernel<<<2 * 1792 + 1, 256, 0, stream>>>(wih[2], whh[2], bih[2], bhh[2],
                                                WihG, WhhG, biasG, 400, 448, 1150, 1152, 64, dflag);
  hipMemsetAsync(cnt, 0, 4096, stream);
  for (int c = 0; c < nch; ++c) {
    gemm_xw_kernel<<<dim3(CH / 2, 14), 256, 0, stream>>>(act2 + (size_t)c * chrows * 1152, WihG, gx, 1152, chrows, 64);
    lstm_rec448<<<56, 512, 0, stream>>>(gx, act3, WhhG, biasG, cnt, cstate, c * CH, CH, chrows);
  }

  unpad_kernel<<<6400, 256, 0, stream>>>(act3, d_out, dflag);
}

// Round 13
// 9564.755 us; speedup vs baseline: 1.1859x; 1.0346x over previous
//
#include <hip/hip_runtime.h>
#include <stdint.h>

typedef _Float16 f16x8 __attribute__((ext_vector_type(8)));
typedef _Float16 f16x4 __attribute__((ext_vector_type(4)));
typedef float f32x4 __attribute__((ext_vector_type(4)));

static __device__ __forceinline__ float bf2f(unsigned short u) {
  return __uint_as_float(((unsigned int)u) << 16);
}
static __device__ __forceinline__ unsigned short f2bf(float f) {
  unsigned int u = __float_as_uint(f);
  u = (u + 0x7FFFu + ((u >> 16) & 1u)) >> 16;  // RNE
  return (unsigned short)u;
}
static __device__ __forceinline__ unsigned short f2h(float f) {
  _Float16 h = (_Float16)f;
  return __builtin_bit_cast(unsigned short, h);
}
static __device__ __forceinline__ float h2f(unsigned short b) {
  _Float16 h = __builtin_bit_cast(_Float16, b);
  return (float)h;
}
static __device__ __forceinline__ float sigm(float x) { return 1.0f / (1.0f + __expf(-x)); }
static __device__ __forceinline__ float tanh_fast(float x) {
  float ax = fabsf(x);
  float e = __expf(-2.0f * ax);
  float r = (1.0f - e) / (1.0f + e);
  return copysignf(r, x);
}

// ---------------- dtype probe: 1 = bf16 inputs, 0 = f32 inputs ----------------
__global__ void probe_kernel(const unsigned int* __restrict__ raw, unsigned int* __restrict__ dflag) {
  __shared__ int s;
  int tid = threadIdx.x;
  if (tid == 0) s = 0;
  __syncthreads();
  int v = 0;
  for (int k = 0; k < 4; ++k) {
    unsigned int d = raw[2048 + tid * 4 + k];
    unsigned int lo = d & 0xFFFFu, ex = (lo >> 7) & 0xFFu;
    if (lo == 0u || (ex >= 0x40u && ex <= 0x7Cu)) v++;
  }
  atomicAdd(&s, v);
  __syncthreads();
  if (tid == 0) dflag[0] = (s >= 614) ? 1u : 0u;
}

// ---------------- embedding -> f16 act0 [32768][448], pad cols -> 0 ----------
__global__ void embed_kernel(const int* __restrict__ x, const void* __restrict__ emb,
                             unsigned short* __restrict__ act, const unsigned int* __restrict__ dflag) {
  int idx = blockIdx.x * 256 + threadIdx.x;  // 32768 rows * 56 chunks
  int row = idx / 56, c = idx % 56;
  unsigned short* dst = act + (size_t)row * 448 + c * 8;
  union { uint4 v; unsigned short s[8]; } o;
  if (c < 50) {
    int tok = x[row];
    if (dflag[0]) {
      const unsigned short* e = (const unsigned short*)emb + (size_t)tok * 400 + c * 8;
      union { uint4 v; unsigned short s[8]; } r; r.v = *(const uint4*)e;
#pragma unroll
      for (int k = 0; k < 8; ++k) o.s[k] = f2h(bf2f(r.s[k]));
    } else {
      const float* e = (const float*)emb + (size_t)tok * 400 + c * 8;
      float4 r0 = *(const float4*)e, r1 = *(const float4*)(e + 4);
      const float* p0 = (const float*)&r0; const float* p1 = (const float*)&r1;
#pragma unroll
      for (int k = 0; k < 4; ++k) { o.s[k] = f2h(p0[k]); o.s[4 + k] = f2h(p1[k]); }
    }
  } else {
    o.v.x = o.v.y = o.v.z = o.v.w = 0u;
  }
  *(uint4*)dst = o.v;
}

// ------------- weights/bias -> GROUP-MAJOR padded f16 layouts -----------------
// Group width GW (96 or 64): row j = G*GW + q*(GW/4) + u <-> unit i = G*(GW/4)+u.
__global__ void prep_kernel(const void* __restrict__ wih, const void* __restrict__ whh,
                            const void* __restrict__ bih, const void* __restrict__ bhh,
                            unsigned short* __restrict__ WihG, unsigned short* __restrict__ WhhG,
                            float* __restrict__ biasG, int H, int HPo, int din, int dpIn, int GW,
                            const unsigned int* __restrict__ dflag) {
  int nb = 4 * HPo, bid = blockIdx.x, tid = threadIdx.x;
  int upg = GW >> 2;
  bool isf32 = (dflag[0] == 0u);
  if (bid < 2 * nb) {
    bool ih = bid < nb;
    int j = ih ? bid : bid - nb;
    int rj = j % GW;
    int i = (j / GW) * upg + rj % upg, q = rj / upg;
    int cdst = ih ? dpIn : HPo, csrc = ih ? din : H;
    unsigned short* dst = (ih ? WihG : WhhG) + (size_t)j * cdst;
    bool valid = i < H;
    const void* w = ih ? wih : whh;
    for (int m = tid; m < cdst; m += 256) {
      unsigned short v = 0;
      if (valid && m < csrc) {
        if (isf32) v = f2h(((const float*)w)[(size_t)(q * H + i) * csrc + m]);
        else       v = f2h(bf2f(((const unsigned short*)w)[(size_t)(q * H + i) * csrc + m]));
      }
      dst[m] = v;
    }
  } else {
    for (int m = tid; m < nb; m += 256) {
      int rj = m % GW;
      int i = (m / GW) * upg + rj % upg, q = rj / upg;
      float v = 0.0f;
      if (i < H) {
        if (isf32) v = ((const float*)bih)[q * H + i] + ((const float*)bhh)[q * H + i];
        else       v = bf2f(((const unsigned short*)bih)[q * H + i]) + bf2f(((const unsigned short*)bhh)[q * H + i]);
      }
      biasG[m] = v;
    }
  }
}

// ---------------- final unpad: act3 f16 [.][448] -> d_out (bf16 or f32) -------
__global__ void unpad_kernel(const unsigned short* __restrict__ act, void* __restrict__ out,
                             const unsigned int* __restrict__ dflag) {
  int idx = blockIdx.x * 256 + threadIdx.x;  // 32768 * 50
  int row = idx / 50, c = idx % 50;
  const unsigned short* src = act + (size_t)row * 448 + c * 8;
  union { uint4 v; unsigned short s[8]; } u; u.v = *(const uint4*)src;
  if (dflag[0]) {
    union { uint4 v; unsigned short s[8]; } o;
#pragma unroll
    for (int k = 0; k < 8; ++k) o.s[k] = f2bf(h2f(u.s[k]));
    *(uint4*)((unsigned short*)out + (size_t)row * 400 + c * 8) = o.v;
  } else {
    float4 o0, o1;
    float* p0 = (float*)&o0; float* p1 = (float*)&o1;
#pragma unroll
    for (int k = 0; k < 4; ++k) { p0[k] = h2f(u.s[k]); p1[k] = h2f(u.s[4 + k]); }
    float* dst = (float*)out + (size_t)row * 400 + c * 8;
    *(float4*)dst = o0; *(float4*)(dst + 4) = o1;
  }
}

// ------------- chunked GEMM: gx = act_chunk @ WihG^T, cell-layout f16 ---------
// BK=64 staging: two 32-k tiles per barrier epoch (2x16KB swizzled LDS buffers).
// Output cell: gx[((size_t)G*chrows + m)*GW + u*4 + q], G=n/GW, u=(n%GW)%(GW/4),
// q=(n%GW)/(GW/4).
__global__ __launch_bounds__(256, 1) void gemm_xw_kernel(
    const unsigned short* __restrict__ A, const unsigned short* __restrict__ B,
    unsigned short* __restrict__ gx, int K, int chrows, int GW) {
  __shared__ unsigned short Asm[2 * 128 * 32], Bsm[2 * 128 * 32];  // 16KB each
  const int tid = threadIdx.x, lane = tid & 63, wv = tid >> 6;
  const int bm0 = blockIdx.x * 128, bn0 = blockIdx.y * 128;
  const int upg = GW >> 2;
  f32x4 acc[2][8] = {};
  const int nke = K >> 6;  // 64-k epochs (448 and 1152 both divisible by 64)
  for (int ke = 0; ke < nke; ++ke) {
    __syncthreads();
#pragma unroll
    for (int hb2 = 0; hb2 < 2; ++hb2) {
#pragma unroll
      for (int j = 0; j < 2; ++j) {
        int idx = tid * 2 + j, r = idx >> 2, c4 = idx & 3;
        uint4 va = *(const uint4*)(A + (size_t)(bm0 + r) * K + (ke * 2 + hb2) * 32 + c4 * 8);
        uint4 vb = *(const uint4*)(B + (size_t)(bn0 + r) * K + (ke * 2 + hb2) * 32 + c4 * 8);
        int off = hb2 * 8192 + ((r * 64 + c4 * 16) ^ ((r & 7) << 4));
        *(uint4*)((char*)Asm + off) = va;
        *(uint4*)((char*)Bsm + off) = vb;
      }
    }
    __syncthreads();
#pragma unroll
    for (int hb2 = 0; hb2 < 2; ++hb2) {
      f16x8 af[2], bf[8];
#pragma unroll
      for (int rt = 0; rt < 2; ++rt) {
        int arow = wv * 32 + rt * 16 + (lane & 15);
        int off = hb2 * 8192 + ((arow * 64 + ((lane >> 4) << 4)) ^ ((arow & 7) << 4));
        af[rt] = *(const f16x8*)((char*)Asm + off);
      }
#pragma unroll
      for (int ct = 0; ct < 8; ++ct) {
        int brow = ct * 16 + (lane & 15);
        int off = hb2 * 8192 + ((brow * 64 + ((lane >> 4) << 4)) ^ ((brow & 7) << 4));
        bf[ct] = *(const f16x8*)((char*)Bsm + off);
      }
#pragma unroll
      for (int rt = 0; rt < 2; ++rt)
#pragma unroll
        for (int ct = 0; ct < 8; ++ct)
          acc[rt][ct] = __builtin_amdgcn_mfma_f32_16x16x32_f16(af[rt], bf[ct], acc[rt][ct], 0, 0, 0);
    }
  }
#pragma unroll
  for (int ct = 0; ct < 8; ++ct) {
    int n = bn0 + ct * 16 + (lane & 15);
    int G = n / GW, c = n % GW;
    int cellcol = (c % upg) * 4 + (c / upg);
#pragma unroll
    for (int rt = 0; rt < 2; ++rt) {
#pragma unroll
      for (int reg = 0; reg < 4; ++reg) {
        int m = bm0 + wv * 32 + rt * 16 + ((lane >> 4) << 2) + reg;
        gx[((size_t)G * chrows + m) * GW + cellcol] = f2h(acc[rt][ct][reg]);
      }
    }
  }
}

// ---------------- rec1152: 24 units x 16 rows per block, 192 blocks ------------
// (PROVEN 9.90 ms configuration — reverted verbatim.)
// bid: G = bid>>2 (24-unit group, 0..47), rq = bid&3 (16-row quarter).
// Row quarters are independent -> 4 counter groups (8 sub-counters, PERQ=6).
// 8 waves = 8 uneven k-slices (4x160 KT=5, 4x128 KT=4). Per-CU h fill:
// 16 rows x 1152 x 2B = 36.9 KB/step. Per-step skeleton:
// poll -> gx -> burst h + MFMA -> LDS-only barrier -> reduce -> publish ->
// vmcnt drain + sync -> release.
__global__ __launch_bounds__(512, 1) void lstm_rec1152(
    const unsigned short* __restrict__ gxAll, unsigned short* __restrict__ actOut,
    const unsigned short* __restrict__ WhhG, const float* __restrict__ biasG,
    unsigned int* __restrict__ cnt, float* __restrict__ cstate,
    int t0, int TS, int chrows) {
  constexpr int HP = 1152, GSTR = 100;
  __shared__ float Gp[128 * GSTR];  // 51,200 B
  const int tid = threadIdx.x, lane = tid & 63, wv = tid >> 6;
  const int lrow = lane & 15, kc8 = (lane >> 4) << 3;
  const int G = blockIdx.x >> 2, rq = blockIdx.x & 3;
  const int k0 = (wv < 4) ? wv * 160 : 640 + (wv - 4) * 128;
  const int urow = tid >> 5, ui = tid & 31;
  const bool red = ui < 24;
  unsigned int* mycnt = cnt + rq * 256;

  f16x8 wreg[6][5];
  {
    const unsigned short* wp = WhhG + ((size_t)(G * 96 + lrow)) * HP + k0 + kc8;
    if (wv < 4) {
#pragma unroll
      for (int cf = 0; cf < 6; ++cf)
#pragma unroll
        for (int kt = 0; kt < 5; ++kt)
          wreg[cf][kt] = *(const f16x8*)(wp + (size_t)cf * 16 * HP + kt * 32);
    } else {
#pragma unroll
      for (int cf = 0; cf < 6; ++cf)
#pragma unroll
        for (int kt = 0; kt < 4; ++kt)
          wreg[cf][kt] = *(const f16x8*)(wp + (size_t)cf * 16 * HP + kt * 32);
    }
  }
  float bs[4] = {0.f, 0.f, 0.f, 0.f};
  float creg = 0.0f;
  if (red) {
#pragma unroll
    for (int q = 0; q < 4; ++q) bs[q] = biasG[G * 96 + q * 24 + ui];
    if (t0 > 0) creg = cstate[(rq * 16 + urow) * HP + G * 24 + ui];
  }
  __syncthreads();

  const int tend = t0 + TS;
  for (int t = t0; t < tend; ++t) {
    // ---- wait for this row-quarter's 48 blocks to publish h(t-1)
    if (t > 0) {
      while (true) {
        int ok = 1;
        if (tid < 8)
          ok = (__hip_atomic_load(mycnt + tid * 32, __ATOMIC_RELAXED, __HIP_MEMORY_SCOPE_AGENT) >= 6u * (unsigned)t);
        if (__syncthreads_and(ok)) break;
        __builtin_amdgcn_s_sleep(1);
      }
      asm volatile("" ::: "memory");
    }
    // ---- gx(t) issued now; consumed in reduce (hides under MFMA phase)
    f16x4 gxv = {};
    if (red)
      gxv = *(const f16x4*)(gxAll + ((size_t)G * chrows + (t - t0) * 64 + rq * 16 + urow) * 96 + ui * 4);
    // ---- h-part: burst-load this wave's 16 rows x k-slice, then MFMA
    if (t > 0) {
      f16x8 hv[5];
      const unsigned short* hp = actOut + ((size_t)(t - 1) * 64 + rq * 16 + lrow) * HP + k0 + kc8;
      f32x4 acc[6] = {};
      if (wv < 4) {
#pragma unroll
        for (int kt = 0; kt < 5; ++kt) hv[kt] = *(const f16x8*)(hp + kt * 32);
#pragma unroll
        for (int kt = 0; kt < 5; ++kt)
#pragma unroll
          for (int cf = 0; cf < 6; ++cf)
            acc[cf] = __builtin_amdgcn_mfma_f32_16x16x32_f16(hv[kt], wreg[cf][kt], acc[cf], 0, 0, 0);
      } else {
#pragma unroll
        for (int kt = 0; kt < 4; ++kt) hv[kt] = *(const f16x8*)(hp + kt * 32);
#pragma unroll
        for (int kt = 0; kt < 4; ++kt)
#pragma unroll
          for (int cf = 0; cf < 6; ++cf)
            acc[cf] = __builtin_amdgcn_mfma_f32_16x16x32_f16(hv[kt], wreg[cf][kt], acc[cf], 0, 0, 0);
      }
      const int br = (lane >> 4) * 4;
#pragma unroll
      for (int cf = 0; cf < 6; ++cf)
#pragma unroll
        for (int r = 0; r < 4; ++r)
          Gp[(wv * 16 + br + r) * GSTR + cf * 16 + lrow] = acc[cf][r];
    }
    // ---- LDS-only barrier: gx load stays in flight (no vmcnt drain)
    asm volatile("s_waitcnt lgkmcnt(0)" ::: "memory");
    __builtin_amdgcn_s_barrier();
    __builtin_amdgcn_sched_barrier(0);
    // ---- reduce + gate update (cell = row urow, unit ui; 384 active threads)
    if (red) {
      float gi = (float)gxv[0] + bs[0], gf = (float)gxv[1] + bs[1];
      float gg = (float)gxv[2] + bs[2], go = (float)gxv[3] + bs[3];
      if (t > 0) {
#pragma unroll
        for (int k = 0; k < 8; ++k) {
          const int base = (k * 16 + urow) * GSTR + ui;
          gi += Gp[base];
          gf += Gp[base + 24];
          gg += Gp[base + 48];
          go += Gp[base + 72];
        }
      }
      float ig = sigm(gi), fg = sigm(gf), gt = tanh_fast(gg), og = sigm(go);
      creg = fg * creg + ig * gt;
      unsigned short hb = f2h(og * tanh_fast(creg));
      int other = __shfl_xor((int)hb, 1);
      if ((ui & 1) == 0) {
        unsigned int pk = ((unsigned)hb & 0xFFFFu) | ((unsigned)other << 16);
        __hip_atomic_store((unsigned int*)(actOut + ((size_t)t * 64 + rq * 16 + urow) * HP + G * 24 + ui),
                           pk, __ATOMIC_RELAXED, __HIP_MEMORY_SCOPE_AGENT);
      }
    }
    // ---- drain h stores, sync, release arrival
    asm volatile("s_waitcnt vmcnt(0)" ::: "memory");
    __syncthreads();
    if (tid == 0)
      __hip_atomic_fetch_add(mycnt + (G & 7) * 32, 1u, __ATOMIC_RELEASE, __HIP_MEMORY_SCOPE_AGENT);
  }
  if (red) cstate[(rq * 16 + urow) * HP + G * 24 + ui] = creg;
}

// ---------------- rec448: R9-proven 16 units x 32 rows, 56 blocks --------------
__global__ __launch_bounds__(512, 1) void lstm_rec448(
    const unsigned short* __restrict__ gxAll, unsigned short* __restrict__ actOut,
    const unsigned short* __restrict__ WhhG, const float* __restrict__ biasG,
    unsigned int* __restrict__ cnt, float* __restrict__ cstate,
    int t0, int TS, int chrows) {
  constexpr int HP = 448, GSTR = 68, KT = 7;
  __shared__ float Gp[64 * GSTR];  // 17,408 B
  const int tid = threadIdx.x, lane = tid & 63, wv = tid >> 6;
  const int kq = wv & 1, t2 = wv >> 1;
  const int nq = t2 & 1, mh = t2 >> 1;
  const int lrow = lane & 15, kc8 = (lane >> 4) << 3;
  const int G = blockIdx.x >> 1, bh = blockIdx.x & 1;
  const int urow = tid >> 4, ui = tid & 15;
  unsigned int* mycnt = cnt + (size_t)bh * 256;

  float bs[4];
  float creg = 0.0f;
  f16x8 wreg[2][KT];
  {
    const unsigned short* wbase = WhhG + (size_t)G * 64 * HP + kq * 224 + kc8;
#pragma unroll
    for (int cf = 0; cf < 2; ++cf) {
      const unsigned short* wp = wbase + (size_t)((nq * 2 + cf) * 16 + lrow) * HP;
#pragma unroll
      for (int kt = 0; kt < KT; ++kt) wreg[cf][kt] = *(const f16x8*)(wp + kt * 32);
    }
#pragma unroll
    for (int q = 0; q < 4; ++q) bs[q] = biasG[G * 64 + q * 16 + ui];
    if (t0 > 0) creg = cstate[(bh * 32 + urow) * HP + G * 16 + ui];
  }
  __syncthreads();

  const int tend = t0 + TS;
  for (int t = t0; t < tend; ++t) {
    if (t > 0) {
      while (true) {
        int ok = 1;
        if (tid < 4)
          ok = (__hip_atomic_load(mycnt + tid * 32, __ATOMIC_RELAXED, __HIP_MEMORY_SCOPE_AGENT) >= 7u * (unsigned)t);
        if (__syncthreads_and(ok)) break;
        __builtin_amdgcn_s_sleep(1);
      }
      asm volatile("" ::: "memory");
    }
    f16x4 gxv = *(const f16x4*)(gxAll + ((size_t)G * chrows + (t - t0) * 64 + bh * 32 + urow) * 64 + ui * 4);
    if (t > 0) {
      f16x8 hv[KT];
      const unsigned short* hp =
          actOut + ((size_t)(t - 1) * 64 + bh * 32 + mh * 16 + lrow) * HP + kq * 224 + kc8;
#pragma unroll
      for (int kt = 0; kt < KT; ++kt) hv[kt] = *(const f16x8*)(hp + kt * 32);
      f32x4 a[2] = {};
#pragma unroll
      for (int kt = 0; kt < KT; ++kt)
#pragma unroll
        for (int cf = 0; cf < 2; ++cf)
          a[cf] = __builtin_amdgcn_mfma_f32_16x16x32_f16(hv[kt], wreg[cf][kt], a[cf], 0, 0, 0);
      const int br = kq * 32 + mh * 16 + (lane >> 4) * 4;
#pragma unroll
      for (int cf = 0; cf < 2; ++cf)
#pragma unroll
        for (int r = 0; r < 4; ++r)
          Gp[(br + r) * GSTR + (nq * 2 + cf) * 16 + lrow] = a[cf][r];
    }
    asm volatile("s_waitcnt lgkmcnt(0)" ::: "memory");
    __builtin_amdgcn_s_barrier();
    __builtin_amdgcn_sched_barrier(0);
    float gi = (float)gxv[0] + bs[0], gf = (float)gxv[1] + bs[1];
    float gg = (float)gxv[2] + bs[2], go = (float)gxv[3] + bs[3];
    if (t > 0) {
#pragma unroll
      for (int k = 0; k < 2; ++k) {
        const int base = (k * 32 + urow) * GSTR + ui;
        gi += Gp[base];
        gf += Gp[base + 16];
        gg += Gp[base + 32];
        go += Gp[base + 48];
      }
    }
    float ig = sigm(gi), fg = sigm(gf), gt = tanh_fast(gg), og = sigm(go);
    creg = fg * creg + ig * gt;
    unsigned short hb = f2h(og * tanh_fast(creg));
    int other = __shfl_xor((int)hb, 1);
    if ((ui & 1) == 0) {
      unsigned int pk = ((unsigned)hb & 0xFFFFu) | ((unsigned)other << 16);
      __hip_atomic_store((unsigned int*)(actOut + ((size_t)t * 64 + bh * 32 + urow) * HP + G * 16 + ui),
                         pk, __ATOMIC_RELAXED, __HIP_MEMORY_SCOPE_AGENT);
    }
    asm volatile("s_waitcnt vmcnt(0)" ::: "memory");
    __syncthreads();
    if (tid == 0)
      __hip_atomic_fetch_add(mycnt + (G & 3) * 32, 1u, __ATOMIC_RELEASE, __HIP_MEMORY_SCOPE_AGENT);
  }
  cstate[(bh * 32 + urow) * HP + G * 16 + ui] = creg;
}

// ------------------------------- host ----------------------------------------
extern "C" void kernel_launch(void* const* d_in, const int* in_sizes, int n_in,
                              void* d_out, int out_size, void* d_ws, size_t ws_size,
                              hipStream_t stream) {
  (void)in_sizes; (void)n_in; (void)out_size;
  const int* x = (const int*)d_in[0];
  const void* emb = d_in[1];
  const void* wih[3] = {d_in[2], d_in[6], d_in[10]};
  const void* whh[3] = {d_in[3], d_in[7], d_in[11]};
  const void* bih[3] = {d_in[4], d_in[8], d_in[12]};
  const void* bhh[3] = {d_in[5], d_in[9], d_in[13]};

  char* ws = (char*)d_ws;
  size_t off = 0;
  unsigned short* act0 = (unsigned short*)(ws + off); off += (size_t)32768 * 448 * 2;
  unsigned short* act1 = (unsigned short*)(ws + off); off += (size_t)32768 * 1152 * 2;
  unsigned short* act2 = (unsigned short*)(ws + off); off += (size_t)32768 * 1152 * 2;
  unsigned short* act3 = act0;  // alias: act0 dead after L0 GEMM chunks
  unsigned short* WihG = (unsigned short*)(ws + off); off += (size_t)4608 * 1152 * 2;
  unsigned short* WhhG = (unsigned short*)(ws + off); off += (size_t)4608 * 1152 * 2;
  float* biasG = (float*)(ws + off); off += (size_t)4608 * 4;
  float* cstate = (float*)(ws + off); off += (size_t)64 * 1152 * 4;
  unsigned int* cnt = (unsigned int*)(ws + off); off += 4096;
  unsigned int* dflag = (unsigned int*)(ws + off); off += 256;
  unsigned short* gx = (unsigned short*)(ws + off);

  // gx chunk sizing from remaining workspace (589,824 B per timestep)
  size_t avail = (ws_size > off) ? (ws_size - off) : 0;
  int CH = 512;
  while (CH > 32 && (size_t)CH * 589824 > avail) CH >>= 1;
  const int chrows = CH * 64, nch = 512 / CH;

  probe_kernel<<<1, 256, 0, stream>>>((const unsigned int*)emb, dflag);
  embed_kernel<<<7168, 256, 0, stream>>>(x, emb, act0, dflag);

  // ---- Layer 0: din 400(->448) -> H 1150(->1152), GW=96 layouts
  prep_kernel<<<2 * 4608 + 1, 256, 0, stream>>>(wih[0], whh[0], bih[0], bhh[0],
                                                WihG, WhhG, biasG, 1150, 1152, 400, 448, 96, dflag);
  hipMemsetAsync(cnt, 0, 4096, stream);
  for (int c = 0; c < nch; ++c) {
    gemm_xw_kernel<<<dim3(CH / 2, 36), 256, 0, stream>>>(act0 + (size_t)c * chrows * 448, WihG, gx, 448, chrows, 96);
    lstm_rec1152<<<192, 512, 0, stream>>>(gx, act1, WhhG, biasG, cnt, cstate, c * CH, CH, chrows);
  }

  // ---- Layer 1: 1150(->1152) -> 1150(->1152), GW=96 layouts
  prep_kernel<<<2 * 4608 + 1, 256, 0, stream>>>(wih[1], whh[1], bih[1], bhh[1],
                                                WihG, WhhG, biasG, 1150, 1152, 1150, 1152, 96, dflag);
  hipMemsetAsync(cnt, 0, 4096, stream);
  for (int c = 0; c < nch; ++c) {
    gemm_xw_kernel<<<dim3(CH / 2, 36), 256, 0, stream>>>(act1 + (size_t)c * chrows * 1152, WihG, gx, 1152, chrows, 96);
    lstm_rec1152<<<192, 512, 0, stream>>>(gx, act2, WhhG, biasG, cnt, cstate, c * CH, CH, chrows);
  }

  // ---- Layer 2: 1150(->1152) -> H 400(->448), GW=64 layouts
  prep_kernel<<<2 * 1792 + 1, 256, 0, stream>>>(wih[2], whh[2], bih[2], bhh[2],
                                                WihG, WhhG, biasG, 400, 448, 1150, 1152, 64, dflag);
  hipMemsetAsync(cnt, 0, 4096, stream);
  for (int c = 0; c < nch; ++c) {
    gemm_xw_kernel<<<dim3(CH / 2, 14), 256, 0, stream>>>(act2 + (size_t)c * chrows * 1152, WihG, gx, 1152, chrows, 64);
    lstm_rec448<<<56, 512, 0, stream>>>(gx, act3, WhhG, biasG, cnt, cstate, c * CH, CH, chrows);
  }

  unpad_kernel<<<6400, 256, 0, stream>>>(act3, d_out, dflag);
}